// Round 11
// baseline (271.459 us; speedup 1.0000x reference)
//
#include <hip/hip_runtime.h>
#include <cstddef>
#include <cstdint>

#define NNODES 100000
#define NEDGES 800000
#define CAP 32          // bucket capacity; in-degree ~ Poisson(8), P(>=33) ~ 1e-5
#define NXCD 8          // dst-space partitions == XCDs; 100000 % 8 == 0
#define NPB (NNODES / NXCD)   // 12500 nodes per bin
#define BINCAP 110592   // per-bin edge capacity; expected 100k +- 0.3k (+33 sigma)

typedef unsigned short u16;
typedef __attribute__((ext_vector_type(8))) short short8;     // 8 x bf16
typedef __attribute__((ext_vector_type(8))) _Float16 half8;   // 8 x f16
typedef __attribute__((ext_vector_type(4))) float f32x4;
typedef __attribute__((ext_vector_type(4))) int int4v;

__device__ __forceinline__ u16 f32_to_bf16(float f) {
    union { float f; uint32_t u; } v; v.f = f;
    uint32_t r = v.u + 0x7FFF + ((v.u >> 16) & 1);   // RNE; inputs finite
    return (u16)(r >> 16);
}
__device__ __forceinline__ u16 f32_to_f16(float f) {
    union { _Float16 h; u16 u; } v; v.h = (_Float16)f;
    return v.u;
}
// per-16-bit unsigned max on a packed word; for finite f16 >= 0 the unsigned
// bit-pattern order == IEEE order, so this is an exact packed f16 max.
__device__ __forceinline__ uint32_t pkmax(uint32_t a, uint32_t b) {
    uint32_t lo = max(a & 0xFFFFu, b & 0xFFFFu);
    uint32_t hi = max(a >> 16, b >> 16);
    return lo | (hi << 16);
}

// ---------------------------------------------------------------------------
// zero-fill (avoids hipMemsetAsync under graph capture)
// ---------------------------------------------------------------------------
__global__ __launch_bounds__(256) void zero_kernel(float4* __restrict__ p, int n4) {
    int i = blockIdx.x * blockDim.x + threadIdx.x;
    const int stride = gridDim.x * blockDim.x;
    for (; i < n4; i += stride) p[i] = make_float4(0.f, 0.f, 0.f, 0.f);
}

// ---------------------------------------------------------------------------
// pass 1: bin edges by dst-range. Each block stages 1024 (d,s) records in
// LDS, bin-sorts via LDS counters + prefix, reserves global space with one
// atomicAdd per bin, copies out in coalesced runs. Pure streaming traffic.
// Record order within a bin is scheduling-dependent -- fine, max is
// order-independent, so the final output is deterministic.
// ---------------------------------------------------------------------------
__global__ __launch_bounds__(256) void bin_kernel(
    const int* __restrict__ src, const int* __restrict__ dst,
    int* __restrict__ gcnt, int* __restrict__ bind, int* __restrict__ bins, int E)
{
    __shared__ int ld[1024], ls[1024];
    __shared__ int lcnt[8], lpre[8], lgb[8];
    const int tid = threadIdx.x;
    const int base = blockIdx.x * 1024;

    if (tid < 8) lcnt[tid] = 0;
    __syncthreads();

    int d[4], s[4], slot[4], b[4];
    int nv = 0;
    if (base + tid * 4 + 3 < E) {
        const int4v dd = *(const int4v*)&dst[base + tid * 4];
        const int4v ss = *(const int4v*)&src[base + tid * 4];
#pragma unroll
        for (int j = 0; j < 4; ++j) { d[j] = dd[j]; s[j] = ss[j]; }
        nv = 4;
    } else {
        for (int j = 0; j < 4; ++j) {
            const int idx = base + tid * 4 + j;
            if (idx < E) { d[nv] = dst[idx]; s[nv] = src[idx]; ++nv; }
        }
    }
#pragma unroll 4
    for (int j = 0; j < nv; ++j) {
        b[j] = d[j] / NPB;
        slot[j] = atomicAdd(&lcnt[b[j]], 1);
    }
    __syncthreads();
    if (tid == 0) {
        int run = 0;
#pragma unroll
        for (int k = 0; k < 8; ++k) { lpre[k] = run; run += lcnt[k]; }
    }
    __syncthreads();
#pragma unroll 4
    for (int j = 0; j < nv; ++j) {
        const int p = lpre[b[j]] + slot[j];
        ld[p] = d[j]; ls[p] = s[j];
    }
    if (tid < 8 && lcnt[tid] > 0) lgb[tid] = atomicAdd(&gcnt[tid], lcnt[tid]);
    __syncthreads();
    const int total = lpre[7] + lcnt[7];
    for (int i = tid; i < total; i += 256) {
        const int d_ = ld[i];
        const int b_ = d_ / NPB;
        const int g = lgb[b_] + (i - lpre[b_]);
        if (g < BINCAP) {           // clamp: memory safety only
            bind[b_ * BINCAP + g] = d_;
            bins[b_ * BINCAP + g] = ls[i];
        }
    }
}

// ---------------------------------------------------------------------------
// pass 2: XCD-group i (blockIdx%8==i, round-robin onto XCD i) consumes only
// bin i: contiguous ~0.8 MB read, scatter into its L2-resident 1.6 MB col2
// slice. Single-writer-XCD -> dirty lines flush once; no stream pollution.
// ---------------------------------------------------------------------------
__global__ __launch_bounds__(256) void scatter_fill_kernel(
    const int* __restrict__ gcnt,
    const int* __restrict__ bind, const int* __restrict__ bins,
    int* __restrict__ deg, int* __restrict__ col2)
{
    const int xcd  = blockIdx.x & (NXCD - 1);
    const int grp  = blockIdx.x >> 3;
    const int ngrp = gridDim.x >> 3;
    int cnt = gcnt[xcd]; if (cnt > BINCAP) cnt = BINCAP;
    const int* bd = bind + xcd * BINCAP;
    const int* bs = bins + xcd * BINCAP;
    for (int i = grp * 256 + threadIdx.x; i < cnt; i += ngrp * 256) {
        const int d = bd[i];
        const int r = atomicAdd(&deg[d], 1);
        if (r < CAP) col2[d * CAP + r] = bs[i];   // clamp: memory safety only
    }
}

// ---------------------------------------------------------------------------
// cast f32 -> bf16 plane. n4 = count/4.
// ---------------------------------------------------------------------------
__global__ __launch_bounds__(256) void bf16_cast_kernel(
    const float4* __restrict__ in, uint2* __restrict__ out, int n4)
{
    int i = blockIdx.x * 256 + threadIdx.x;
    const int stride = gridDim.x * 256;
    for (; i < n4; i += stride) {
        float4 v = in[i];
        out[i] = make_uint2(
            (uint32_t)f32_to_bf16(v.x) | ((uint32_t)f32_to_bf16(v.y) << 16),
            (uint32_t)f32_to_bf16(v.z) | ((uint32_t)f32_to_bf16(v.w) << 16));
    }
}

// ---------------------------------------------------------------------------
// transpose + round all 9 weight matrices: W[K=128][DO] f32 -> WT[DO][128] u16.
// widx 0=Wp0 1=Ws0 2=Wn0 3=Wp1 4=Ws1 5=Wn1 6=Wp2 7=Ws2(DO64) 8=Wn2(DO64).
// Wn matrices (2,5,8) -> f16 (multiply the f16 agg); others -> bf16.
// ---------------------------------------------------------------------------
struct WPtrs { const float* w[9]; };

__global__ __launch_bounds__(256) void split_weights_kernel(WPtrs p, u16* __restrict__ wbase)
{
    const int idx = blockIdx.x * 256 + threadIdx.x;
    const int w = blockIdx.y;
    const int DO_ = (w >= 7) ? 64 : 128;
    if (idx >= 128 * DO_) return;
    const float v = p.w[w][idx];
    const int k = idx / DO_;
    const int c = idx - k * DO_;
    const bool use_f16 = (w == 2 || w == 5 || w == 8);
    wbase[w * 32768 + c * 128 + k] = use_f16 ? f32_to_f16(v) : f32_to_bf16(v);
}

// ---------------------------------------------------------------------------
// copy final-layer weights (WT7, WT8: 64x128 u16 each) out of d_out scratch
// into a dead d_ws plane so the fused final GEMM can write d_out race-free.
// ---------------------------------------------------------------------------
__global__ __launch_bounds__(256) void copy_w_kernel(
    const uint32_t* __restrict__ w7, const uint32_t* __restrict__ w8,
    uint32_t* __restrict__ dstw)
{
    int i = blockIdx.x * 256 + threadIdx.x;   // 8192 u32 total
    if (i < 4096) dstw[i] = w7[i];
    else if (i < 8192) dstw[i] = w8[i - 4096];
}

// ---------------------------------------------------------------------------
// MFMA GEMM: out[N,DO] = relu( A@Wa (+ C@Wb) + bias ), K=128.
// A: bf16 plane [N][128]. C: f16 plane. W: transposed [DO][128] u16, staged
// in LDS once per block (pad stride 136 -> benign 2-way bank alias).
// Block = 8 waves x 32 rows (2 M-tiles) = 256 rows.
// OUT_MODE: 0 = f32, 1 = bf16 plane, 2 = f16 plane, 3 = fused log_softmax
// -> f32 (DO=64 only).
// ---------------------------------------------------------------------------
template<int DO, bool DUAL, int OUT_MODE>
__global__ __launch_bounds__(512, 4) void mfma_gemm_kernel(
    const u16* __restrict__ A,
    const u16* __restrict__ Cq,
    const u16* __restrict__ WaT, const u16* __restrict__ WbT,
    const float* __restrict__ bias,
    float* __restrict__ outF, u16* __restrict__ outU,
    int N)
{
    constexpr int CT = DO / 16;
    constexpr int WS = 136;                       // padded u16 row stride
    __shared__ u16 sW[(DUAL ? 2 : 1) * DO * WS];

    const int tid = threadIdx.x;

    // ---- stage W (transposed [DO][128]) into LDS
    for (int i = tid; i < DO * 16; i += 512) {
        const int r = i >> 4;
        const int c = (i & 15) << 3;
        *(short8*)&sW[r * WS + c] = *(const short8*)&WaT[r * 128 + c];
        if constexpr (DUAL)
            *(short8*)&sW[DO * WS + r * WS + c] = *(const short8*)&WbT[r * 128 + c];
    }

    const int lane = tid & 63;
    const int wid  = tid >> 6;                    // 0..7
    const int l15  = lane & 15;
    const int lk   = (lane >> 4) << 3;            // 0,8,16,24
    const int row0 = blockIdx.x * 256 + wid * 32;

    int aoff0, aoff1;
    {
        int r0 = row0 + l15;      if (r0 > N - 1) r0 = N - 1;
        int r1 = row0 + 16 + l15; if (r1 > N - 1) r1 = N - 1;
        aoff0 = r0 * 128 + lk;
        aoff1 = r1 * 128 + lk;
    }

    f32x4 acc[2][CT];
#pragma unroll
    for (int m = 0; m < 2; ++m)
#pragma unroll
        for (int c = 0; c < CT; ++c) acc[m][c] = (f32x4){0.f, 0.f, 0.f, 0.f};

    __syncthreads();

#pragma unroll
    for (int k = 0; k < 4; ++k) {
        const int ko = 32 * k;
        short8 ah0 = *(const short8*)(A + aoff0 + ko);
        short8 ah1 = *(const short8*)(A + aoff1 + ko);
        half8 ch0, ch1;
        if constexpr (DUAL) {
            ch0 = *(const half8*)(Cq + aoff0 + ko);
            ch1 = *(const half8*)(Cq + aoff1 + ko);
        }
#pragma unroll
        for (int ct = 0; ct < CT; ++ct) {
            const int wb = (ct * 16 + l15) * WS + lk + ko;
            short8 wh = *(const short8*)&sW[wb];
            acc[0][ct] = __builtin_amdgcn_mfma_f32_16x16x32_bf16(ah0, wh, acc[0][ct], 0, 0, 0);
            acc[1][ct] = __builtin_amdgcn_mfma_f32_16x16x32_bf16(ah1, wh, acc[1][ct], 0, 0, 0);
            if constexpr (DUAL) {
                half8 vh = *(const half8*)&sW[DO * WS + wb];
                acc[0][ct] = __builtin_amdgcn_mfma_f32_16x16x32_f16(ch0, vh, acc[0][ct], 0, 0, 0);
                acc[1][ct] = __builtin_amdgcn_mfma_f32_16x16x32_f16(ch1, vh, acc[1][ct], 0, 0, 0);
            }
        }
    }

    // ---- epilogue: D frag row = (lane>>4)*4 + j, col = l15 (m89 layout)
    float bv[CT];
#pragma unroll
    for (int ct = 0; ct < CT; ++ct) bv[ct] = bias[ct * 16 + l15];

    const int jrow = (lane >> 4) << 2;
#pragma unroll
    for (int m = 0; m < 2; ++m) {
#pragma unroll
        for (int j = 0; j < 4; ++j) {
            const int r = row0 + m * 16 + jrow + j;
            if constexpr (OUT_MODE == 3) {
                // fused log_softmax over DO=64: this row's 64 values live in
                // the 16 lanes sharing (lane>>4) -> shfl_xor 1,2,4,8 reduce.
                float v[CT];
                float mx = 0.f;   // post-relu values >= 0
#pragma unroll
                for (int ct = 0; ct < CT; ++ct) {
                    v[ct] = fmaxf(acc[m][ct][j] + bv[ct], 0.f);
                    mx = fmaxf(mx, v[ct]);
                }
#pragma unroll
                for (int off = 1; off < 16; off <<= 1) mx = fmaxf(mx, __shfl_xor(mx, off));
                float s = 0.f;
#pragma unroll
                for (int ct = 0; ct < CT; ++ct) s += __expf(v[ct] - mx);
#pragma unroll
                for (int off = 1; off < 16; off <<= 1) s += __shfl_xor(s, off);
                const float lse = mx + __logf(s);
                if (r < N) {
#pragma unroll
                    for (int ct = 0; ct < CT; ++ct)
                        outF[(size_t)r * DO + ct * 16 + l15] = v[ct] - lse;
                }
            } else if (r < N) {
#pragma unroll
                for (int ct = 0; ct < CT; ++ct) {
                    float v = fmaxf(acc[m][ct][j] + bv[ct], 0.f);
                    const size_t o = (size_t)r * DO + ct * 16 + l15;
                    if constexpr (OUT_MODE == 0) {
                        outF[o] = v;
                    } else if constexpr (OUT_MODE == 1) {
                        outU[o] = f32_to_bf16(v);
                    } else if constexpr (OUT_MODE == 2) {
                        outU[o] = f32_to_f16(v);
                    }
                }
            }
        }
    }
}

// ---------------------------------------------------------------------------
// gather-max, MLP-optimized: 4 nodes per wave, 16 lanes per node, uint4
// (16 B = 8 f16) per lane -> 16 independent row-gathers in flight per wave.
// pkmax = per-16-bit unsigned max: exact for finite >= 0. Zero in-degree -> 0.
// m/agg layout: [N][16] uint4 == [N][128] f16.
// ---------------------------------------------------------------------------
__global__ __launch_bounds__(256) void aggregate_kernel(
    const uint4* __restrict__ m4,
    const int* __restrict__ deg,
    const int* __restrict__ col2,
    uint4* __restrict__ agg4, int N)
{
    const int tid  = threadIdx.x;
    const int l16  = tid & 15;                       // 16 B chunk within row
    const int node = (blockIdx.x * 256 + tid) >> 4;  // 16 nodes per block
    if (node >= N) return;
    int cnt = deg[node];
    if (cnt > CAP) cnt = CAP;
    const int base = node * CAP;

    uint32_t a0 = 0, a1 = 0, a2 = 0, a3 = 0;
    int e = 0;
    for (; e + 4 <= cnt; e += 4) {
        const int s0 = col2[base + e],     s1 = col2[base + e + 1];
        const int s2 = col2[base + e + 2], s3 = col2[base + e + 3];
        const uint4 v0 = m4[(size_t)s0 * 16 + l16];
        const uint4 v1 = m4[(size_t)s1 * 16 + l16];
        const uint4 v2 = m4[(size_t)s2 * 16 + l16];
        const uint4 v3 = m4[(size_t)s3 * 16 + l16];
        a0 = pkmax(a0, v0.x); a1 = pkmax(a1, v0.y); a2 = pkmax(a2, v0.z); a3 = pkmax(a3, v0.w);
        a0 = pkmax(a0, v1.x); a1 = pkmax(a1, v1.y); a2 = pkmax(a2, v1.z); a3 = pkmax(a3, v1.w);
        a0 = pkmax(a0, v2.x); a1 = pkmax(a1, v2.y); a2 = pkmax(a2, v2.z); a3 = pkmax(a3, v2.w);
        a0 = pkmax(a0, v3.x); a1 = pkmax(a1, v3.y); a2 = pkmax(a2, v3.z); a3 = pkmax(a3, v3.w);
    }
    for (; e < cnt; ++e) {
        const uint4 v0 = m4[(size_t)col2[base + e] * 16 + l16];
        a0 = pkmax(a0, v0.x); a1 = pkmax(a1, v0.y); a2 = pkmax(a2, v0.z); a3 = pkmax(a3, v0.w);
    }
    agg4[(size_t)node * 16 + l16] = make_uint4(a0, a1, a2, a3);
}

// ---------------------------------------------------------------------------
extern "C" void kernel_launch(void* const* d_in, const int* in_sizes, int n_in,
                              void* d_out, int out_size, void* d_ws, size_t ws_size,
                              hipStream_t stream)
{
    const int N = NNODES, E = NEDGES;
    const float* x  = (const float*)d_in[0];
    const int* esrc = (const int*)d_in[1];
    const int* edst = (const int*)d_in[2];
    const float* bp[3] = {(const float*)d_in[4], (const float*)d_in[9],  (const float*)d_in[14]};
    const float* bn[3] = {(const float*)d_in[7], (const float*)d_in[12], (const float*)d_in[17]};

    // d_ws planes of N*128*2 B = 25.6 MB (153.6 MB total, proven layout).
    // p0/p2: h ping-pong (bf16); p4: m (f16) + final W copy; p5: agg (f16).
    char* ws = (char*)d_ws;
    const size_t P = (size_t)N * 128 * 2;
    u16* p0 = (u16*)(ws);
    u16* p2 = (u16*)(ws + 2 * P);
    u16* p4 = (u16*)(ws + 4 * P);
    u16* p5 = (u16*)(ws + 5 * P);

    // scratch in d_out (25.6 MB): deg+gcnt | col2 | weights | bins. All dead
    // before the fused final GEMM writes d_out (weights copied to p4 first).
    char* ob = (char*)d_out;
    int* deg    = (int*)ob;                          // 100000 ints
    int* gcnt   = (int*)(ob + 400000);               // 8 ints (inside zeroed 409600)
    int* col2   = (int*)(ob + 409600);               // N*CAP ints = 12.8 MB
    u16* wbase  = (u16*)(ob + 409600 + (size_t)N * CAP * 4);      // 9*64KB
    int* bind   = (int*)(ob + 13800448);             // 8*BINCAP ints = 3.54 MB
    int* bins   = (int*)(ob + 13800448 + 8 * BINCAP * 4);         // 3.54 MB
    auto WT = [&](int i) { return wbase + i * 32768; };

    const int gblocks = (N + 255) / 256;      // 391 (256 rows/block, 32/wave)
    const int ablocks = (N * 16 + 255) / 256; // 6250 (16 nodes/block)
    const int bblocks = (E + 1023) / 1024;    // 782
    dim3 blk(256), gblk(512);

    // ---- adjacency: zero counters, bin edges, per-XCD scatter
    zero_kernel<<<128, blk, 0, stream>>>((float4*)ob, 409600 / 16);
    bin_kernel<<<bblocks, blk, 0, stream>>>(esrc, edst, gcnt, bind, bins, E);
    scatter_fill_kernel<<<2048, blk, 0, stream>>>(gcnt, bind, bins, deg, col2);

    WPtrs wp;
    wp.w[0] = (const float*)d_in[3];  wp.w[1] = (const float*)d_in[5];  wp.w[2] = (const float*)d_in[6];
    wp.w[3] = (const float*)d_in[8];  wp.w[4] = (const float*)d_in[10]; wp.w[5] = (const float*)d_in[11];
    wp.w[6] = (const float*)d_in[13]; wp.w[7] = (const float*)d_in[15]; wp.w[8] = (const float*)d_in[16];
    split_weights_kernel<<<dim3(64, 9), blk, 0, stream>>>(wp, wbase);
    bf16_cast_kernel<<<2048, blk, 0, stream>>>((const float4*)x, (uint2*)p0, N * 128 / 4);

    // ---- layer 0: h = p0
    mfma_gemm_kernel<128, false, 2><<<gblocks, gblk, 0, stream>>>(
        p0, nullptr, WT(0), nullptr, bp[0], nullptr, p4, N);
    aggregate_kernel<<<ablocks, blk, 0, stream>>>((const uint4*)p4, deg, col2, (uint4*)p5, N);
    mfma_gemm_kernel<128, true, 1><<<gblocks, gblk, 0, stream>>>(
        p0, p5, WT(1), WT(2), bn[0], nullptr, p2, N);

    // ---- layer 1: h = p2
    mfma_gemm_kernel<128, false, 2><<<gblocks, gblk, 0, stream>>>(
        p2, nullptr, WT(3), nullptr, bp[1], nullptr, p4, N);
    aggregate_kernel<<<ablocks, blk, 0, stream>>>((const uint4*)p4, deg, col2, (uint4*)p5, N);
    mfma_gemm_kernel<128, true, 1><<<gblocks, gblk, 0, stream>>>(
        p2, p5, WT(4), WT(5), bn[1], nullptr, p0, N);

    // ---- layer 2: h = p0, DO=64, fused log_softmax -> d_out
    mfma_gemm_kernel<128, false, 2><<<gblocks, gblk, 0, stream>>>(
        p0, nullptr, WT(6), nullptr, bp[2], nullptr, p4, N);
    aggregate_kernel<<<ablocks, blk, 0, stream>>>((const uint4*)p4, deg, col2, (uint4*)p5, N);
    // weights out of d_out (m in p4 is dead now); then fused GEMM owns d_out
    copy_w_kernel<<<32, blk, 0, stream>>>((const uint32_t*)WT(7), (const uint32_t*)WT(8), (uint32_t*)p4);
    mfma_gemm_kernel<64, true, 3><<<gblocks, gblk, 0, stream>>>(
        p0, p5, p4, p4 + 8192, bn[2], (float*)d_out, nullptr, N);
}

// Round 12
// 269.653 us; speedup vs baseline: 1.0067x; 1.0067x over previous
//
#include <hip/hip_runtime.h>
#include <cstddef>
#include <cstdint>

#define NNODES 100000
#define NEDGES 800000
#define CAP 32          // bucket capacity; in-degree ~ Poisson(8), P(>=33) ~ 1e-5
#define NXCD 8          // dst-space partitions == XCDs; 100000 % 8 == 0
#define NPB (NNODES / NXCD)   // 12500 nodes per bin
#define BINCAP 110592   // per-bin edge capacity; expected 100k +- 0.3k (+33 sigma)

typedef unsigned short u16;
typedef __attribute__((ext_vector_type(8))) short short8;     // 8 x bf16
typedef __attribute__((ext_vector_type(8))) _Float16 half8;   // 8 x f16
typedef __attribute__((ext_vector_type(4))) float f32x4;
typedef __attribute__((ext_vector_type(4))) int int4v;

__device__ __forceinline__ u16 f32_to_bf16(float f) {
    union { float f; uint32_t u; } v; v.f = f;
    uint32_t r = v.u + 0x7FFF + ((v.u >> 16) & 1);   // RNE; inputs finite
    return (u16)(r >> 16);
}
__device__ __forceinline__ u16 f32_to_f16(float f) {
    union { _Float16 h; u16 u; } v; v.h = (_Float16)f;
    return v.u;
}
// per-16-bit unsigned max on a packed word; for finite f16 >= 0 the unsigned
// bit-pattern order == IEEE order, so this is an exact packed f16 max.
__device__ __forceinline__ uint32_t pkmax(uint32_t a, uint32_t b) {
    uint32_t lo = max(a & 0xFFFFu, b & 0xFFFFu);
    uint32_t hi = max(a >> 16, b >> 16);
    return lo | (hi << 16);
}
__device__ __forceinline__ void agmax(uint4& a, uint4 v) {
    a.x = pkmax(a.x, v.x); a.y = pkmax(a.y, v.y);
    a.z = pkmax(a.z, v.z); a.w = pkmax(a.w, v.w);
}

// gather-max of one node row into 4 register chunks (lane owns chunk `sec+4k`
// of the 16-uint4 f16 row). 2-edge unrolled -> 8 outstanding 16B gathers.
__device__ __forceinline__ void gather_row(
    uint4 (&ag)[4], const uint4* __restrict__ m4,
    const int* __restrict__ deg, const int* __restrict__ col2, int row, int sec)
{
    int cnt = deg[row]; if (cnt > CAP) cnt = CAP;
    const int base = row * CAP;
    int e = 0;
    for (; e + 2 <= cnt; e += 2) {
        const uint4* q0 = m4 + (size_t)col2[base + e] * 16 + sec;
        const uint4* q1 = m4 + (size_t)col2[base + e + 1] * 16 + sec;
        uint4 v00 = q0[0], v01 = q0[4], v02 = q0[8], v03 = q0[12];
        uint4 v10 = q1[0], v11 = q1[4], v12 = q1[8], v13 = q1[12];
        agmax(ag[0], v00); agmax(ag[1], v01); agmax(ag[2], v02); agmax(ag[3], v03);
        agmax(ag[0], v10); agmax(ag[1], v11); agmax(ag[2], v12); agmax(ag[3], v13);
    }
    if (e < cnt) {
        const uint4* q0 = m4 + (size_t)col2[base + e] * 16 + sec;
        agmax(ag[0], q0[0]); agmax(ag[1], q0[4]); agmax(ag[2], q0[8]); agmax(ag[3], q0[12]);
    }
}

// ---------------------------------------------------------------------------
// zero-fill (avoids hipMemsetAsync under graph capture)
// ---------------------------------------------------------------------------
__global__ __launch_bounds__(256) void zero_kernel(float4* __restrict__ p, int n4) {
    int i = blockIdx.x * blockDim.x + threadIdx.x;
    const int stride = gridDim.x * blockDim.x;
    for (; i < n4; i += stride) p[i] = make_float4(0.f, 0.f, 0.f, 0.f);
}

// ---------------------------------------------------------------------------
// pass 1: bin edges by dst-range (LDS bin-sort per 1024-edge block, one
// global atomicAdd per bin per block, coalesced copy-out). Record order
// within a bin is scheduling-dependent -- fine, max is order-independent.
// ---------------------------------------------------------------------------
__global__ __launch_bounds__(256) void bin_kernel(
    const int* __restrict__ src, const int* __restrict__ dst,
    int* __restrict__ gcnt, int* __restrict__ bind, int* __restrict__ bins, int E)
{
    __shared__ int ld[1024], ls[1024];
    __shared__ int lcnt[8], lpre[8], lgb[8];
    const int tid = threadIdx.x;
    const int base = blockIdx.x * 1024;

    if (tid < 8) lcnt[tid] = 0;
    __syncthreads();

    int d[4], s[4], slot[4], b[4];
    int nv = 0;
    if (base + tid * 4 + 3 < E) {
        const int4v dd = *(const int4v*)&dst[base + tid * 4];
        const int4v ss = *(const int4v*)&src[base + tid * 4];
#pragma unroll
        for (int j = 0; j < 4; ++j) { d[j] = dd[j]; s[j] = ss[j]; }
        nv = 4;
    } else {
        for (int j = 0; j < 4; ++j) {
            const int idx = base + tid * 4 + j;
            if (idx < E) { d[nv] = dst[idx]; s[nv] = src[idx]; ++nv; }
        }
    }
#pragma unroll 4
    for (int j = 0; j < nv; ++j) {
        b[j] = d[j] / NPB;
        slot[j] = atomicAdd(&lcnt[b[j]], 1);
    }
    __syncthreads();
    if (tid == 0) {
        int run = 0;
#pragma unroll
        for (int k = 0; k < 8; ++k) { lpre[k] = run; run += lcnt[k]; }
    }
    __syncthreads();
#pragma unroll 4
    for (int j = 0; j < nv; ++j) {
        const int p = lpre[b[j]] + slot[j];
        ld[p] = d[j]; ls[p] = s[j];
    }
    if (tid < 8 && lcnt[tid] > 0) lgb[tid] = atomicAdd(&gcnt[tid], lcnt[tid]);
    __syncthreads();
    const int total = lpre[7] + lcnt[7];
    for (int i = tid; i < total; i += 256) {
        const int d_ = ld[i];
        const int b_ = d_ / NPB;
        const int g = lgb[b_] + (i - lpre[b_]);
        if (g < BINCAP) {           // clamp: memory safety only
            bind[b_ * BINCAP + g] = d_;
            bins[b_ * BINCAP + g] = ls[i];
        }
    }
}

// ---------------------------------------------------------------------------
// pass 2: XCD-group i (blockIdx%8==i) consumes only bin i: contiguous read,
// scatter into its L2-resident col2 slice. Single-writer-XCD.
// ---------------------------------------------------------------------------
__global__ __launch_bounds__(256) void scatter_fill_kernel(
    const int* __restrict__ gcnt,
    const int* __restrict__ bind, const int* __restrict__ bins,
    int* __restrict__ deg, int* __restrict__ col2)
{
    const int xcd  = blockIdx.x & (NXCD - 1);
    const int grp  = blockIdx.x >> 3;
    const int ngrp = gridDim.x >> 3;
    int cnt = gcnt[xcd]; if (cnt > BINCAP) cnt = BINCAP;
    const int* bd = bind + xcd * BINCAP;
    const int* bs = bins + xcd * BINCAP;
    for (int i = grp * 256 + threadIdx.x; i < cnt; i += ngrp * 256) {
        const int d = bd[i];
        const int r = atomicAdd(&deg[d], 1);
        if (r < CAP) col2[d * CAP + r] = bs[i];   // clamp: memory safety only
    }
}

// ---------------------------------------------------------------------------
// transpose + round all 9 weight matrices: W[K=128][DO] f32 -> WT[DO][128] u16.
// widx 0=Wp0 1=Ws0 2=Wn0 3=Wp1 4=Ws1 5=Wn1 6=Wp2 7=Ws2(DO64) 8=Wn2(DO64).
// Wn matrices (2,5,8) -> f16 (multiply the f16 agg); others -> bf16.
// ---------------------------------------------------------------------------
struct WPtrs { const float* w[9]; };

__global__ __launch_bounds__(256) void split_weights_kernel(WPtrs p, u16* __restrict__ wbase)
{
    const int idx = blockIdx.x * 256 + threadIdx.x;
    const int w = blockIdx.y;
    const int DO_ = (w >= 7) ? 64 : 128;
    if (idx >= 128 * DO_) return;
    const float v = p.w[w][idx];
    const int k = idx / DO_;
    const int c = idx - k * DO_;
    const bool use_f16 = (w == 2 || w == 5 || w == 8);
    wbase[w * 32768 + c * 128 + k] = use_f16 ? f32_to_f16(v) : f32_to_bf16(v);
}

// ---------------------------------------------------------------------------
// MFMA GEMM with optional fused gather-max neighbor operand.
//   out[N,DO] = relu( A@Wa (+ segmax(m)@Wb) + bias ), K=128.
// A: bf16 [N][128] (or f32 when AF32: converted in-flight, bit-identical to
// the old cast kernel). W: transposed [DO][128] u16 in LDS.
// DUAL: C-fragment built by in-register gather-max over in-edges (exact f16
// max via pkmax); waves then handle 1 M-tile (16 rows) to keep VGPRs in
// budget; single keeps 2 M-tiles.
// OUT_MODE: 1 = bf16 plane, 2 = f16 plane, 3 = fused log_softmax -> f32.
// ---------------------------------------------------------------------------
template<int DO, bool DUAL, int OUT_MODE, bool AF32>
__global__ __launch_bounds__(512, 4) void mfma_gemm_kernel(
    const void* __restrict__ Av,
    const int* __restrict__ deg, const int* __restrict__ col2,
    const uint4* __restrict__ m4,
    const u16* __restrict__ WaT, const u16* __restrict__ WbT,
    const float* __restrict__ bias,
    float* __restrict__ outF, u16* __restrict__ outU, int N)
{
    constexpr int CT = DO / 16;
    constexpr int MT = DUAL ? 1 : 2;              // M-tiles per wave
    constexpr int WS = 136;                       // padded u16 row stride
    __shared__ u16 sW[(DUAL ? 2 : 1) * DO * WS];

    const int tid = threadIdx.x;

    // ---- stage W (transposed [DO][128]) into LDS
    for (int i = tid; i < DO * 16; i += 512) {
        const int r = i >> 4;
        const int c = (i & 15) << 3;
        *(short8*)&sW[r * WS + c] = *(const short8*)&WaT[r * 128 + c];
        if constexpr (DUAL)
            *(short8*)&sW[DO * WS + r * WS + c] = *(const short8*)&WbT[r * 128 + c];
    }

    const int lane = tid & 63;
    const int wid  = tid >> 6;                    // 0..7
    const int l15  = lane & 15;
    const int sec  = lane >> 4;                   // 0..3
    const int lk   = sec << 3;                    // 0,8,16,24
    const int row0 = blockIdx.x * (128 * MT) + wid * (16 * MT);

    int rc[MT], aoff[MT];
#pragma unroll
    for (int m = 0; m < MT; ++m) {
        int r = row0 + m * 16 + l15; if (r > N - 1) r = N - 1;
        rc[m] = r;
        aoff[m] = r * 128 + lk;
    }

    // ---- fused gather-max (DUAL): C-fragments for this lane's row
    uint4 ag[MT][4];
    if constexpr (DUAL) {
#pragma unroll
        for (int m = 0; m < MT; ++m)
#pragma unroll
            for (int k = 0; k < 4; ++k) ag[m][k] = make_uint4(0, 0, 0, 0);
#pragma unroll
        for (int m = 0; m < MT; ++m)
            gather_row(ag[m], m4, deg, col2, rc[m], sec);
    }

    f32x4 acc[MT][CT];
#pragma unroll
    for (int m = 0; m < MT; ++m)
#pragma unroll
        for (int c = 0; c < CT; ++c) acc[m][c] = (f32x4){0.f, 0.f, 0.f, 0.f};

    __syncthreads();

#pragma unroll
    for (int k = 0; k < 4; ++k) {
        const int ko = 32 * k;
        short8 ah[MT];
#pragma unroll
        for (int m = 0; m < MT; ++m) {
            if constexpr (AF32) {
                const float* pa = (const float*)Av + aoff[m] + ko;
                f32x4 a = *(const f32x4*)pa;
                f32x4 b = *(const f32x4*)(pa + 4);
#pragma unroll
                for (int j = 0; j < 4; ++j) {
                    ah[m][j]     = (short)f32_to_bf16(a[j]);
                    ah[m][j + 4] = (short)f32_to_bf16(b[j]);
                }
            } else {
                ah[m] = *(const short8*)((const u16*)Av + aoff[m] + ko);
            }
        }
        half8 ch[MT];
        if constexpr (DUAL) {
#pragma unroll
            for (int m = 0; m < MT; ++m) {
                union { uint4 u; half8 h; } t; t.u = ag[m][k];
                ch[m] = t.h;
            }
        }
#pragma unroll
        for (int ct = 0; ct < CT; ++ct) {
            const int wb = (ct * 16 + l15) * WS + lk + ko;
            short8 wh = *(const short8*)&sW[wb];
#pragma unroll
            for (int m = 0; m < MT; ++m)
                acc[m][ct] = __builtin_amdgcn_mfma_f32_16x16x32_bf16(ah[m], wh, acc[m][ct], 0, 0, 0);
            if constexpr (DUAL) {
                half8 vh = *(const half8*)&sW[DO * WS + wb];
#pragma unroll
                for (int m = 0; m < MT; ++m)
                    acc[m][ct] = __builtin_amdgcn_mfma_f32_16x16x32_f16(ch[m], vh, acc[m][ct], 0, 0, 0);
            }
        }
    }

    // ---- epilogue: D frag row = sec*4 + j, col = l15 (m89 layout)
    float bv[CT];
#pragma unroll
    for (int ct = 0; ct < CT; ++ct) bv[ct] = bias[ct * 16 + l15];

    const int jrow = sec << 2;
#pragma unroll
    for (int m = 0; m < MT; ++m) {
#pragma unroll
        for (int j = 0; j < 4; ++j) {
            const int r = row0 + m * 16 + jrow + j;
            if constexpr (OUT_MODE == 3) {
                // fused log_softmax over DO=64: row's 64 values live in the
                // 16 lanes sharing sec -> shfl_xor 1,2,4,8 reduce.
                float v[CT];
                float mx = 0.f;   // post-relu values >= 0
#pragma unroll
                for (int ct = 0; ct < CT; ++ct) {
                    v[ct] = fmaxf(acc[m][ct][j] + bv[ct], 0.f);
                    mx = fmaxf(mx, v[ct]);
                }
#pragma unroll
                for (int off = 1; off < 16; off <<= 1) mx = fmaxf(mx, __shfl_xor(mx, off));
                float s = 0.f;
#pragma unroll
                for (int ct = 0; ct < CT; ++ct) s += __expf(v[ct] - mx);
#pragma unroll
                for (int off = 1; off < 16; off <<= 1) s += __shfl_xor(s, off);
                const float lse = mx + __logf(s);
                if (r < N) {
#pragma unroll
                    for (int ct = 0; ct < CT; ++ct)
                        outF[(size_t)r * DO + ct * 16 + l15] = v[ct] - lse;
                }
            } else if (r < N) {
#pragma unroll
                for (int ct = 0; ct < CT; ++ct) {
                    float v = fmaxf(acc[m][ct][j] + bv[ct], 0.f);
                    const size_t o = (size_t)r * DO + ct * 16 + l15;
                    if constexpr (OUT_MODE == 1) {
                        outU[o] = f32_to_bf16(v);
                    } else {
                        outU[o] = f32_to_f16(v);
                    }
                }
            }
        }
    }
}

// ---------------------------------------------------------------------------
extern "C" void kernel_launch(void* const* d_in, const int* in_sizes, int n_in,
                              void* d_out, int out_size, void* d_ws, size_t ws_size,
                              hipStream_t stream)
{
    const int N = NNODES, E = NEDGES;
    const float* x  = (const float*)d_in[0];
    const int* esrc = (const int*)d_in[1];
    const int* edst = (const int*)d_in[2];
    const float* bp[3] = {(const float*)d_in[4], (const float*)d_in[9],  (const float*)d_in[14]};
    const float* bn[3] = {(const float*)d_in[7], (const float*)d_in[12], (const float*)d_in[17]};

    // ALL scratch in d_ws (153.6 MB = 6 planes of 25.6 MB); d_out is written
    // only by the final fused GEMM -> no race, no copies.
    char* ws = (char*)d_ws;
    const size_t P = (size_t)N * 128 * 2;
    u16* p0 = (u16*)(ws);                    // h ping (bf16)
    char* p1 = ws + P;                       // deg(+gcnt) | col2
    u16* p2 = (u16*)(ws + 2 * P);            // h pong (bf16)
    char* p3 = ws + 3 * P;                   // bind | bins
    u16* p4 = (u16*)(ws + 4 * P);            // m (f16 [N][128])
    u16* p5 = (u16*)(ws + 5 * P);            // weights (9 x 64 KB)

    int* deg  = (int*)p1;                    // 100000 ints
    int* gcnt = (int*)(p1 + 400000);         // 8 ints (inside zeroed 409600 B)
    int* col2 = (int*)(p1 + 409600);         // N*CAP ints = 12.8 MB
    int* bind = (int*)p3;                    // 8*BINCAP ints = 3.54 MB
    int* bins = bind + 8 * BINCAP;           // 3.54 MB
    u16* wbase = p5;
    auto WT = [&](int i) { return wbase + i * 32768; };

    const int gs = (N + 255) / 256;          // 391 single-GEMM blocks (256 rows)
    const int gd = (N + 127) / 128;          // 782 dual-GEMM blocks (128 rows)
    const int bblocks = (E + 1023) / 1024;   // 782
    dim3 blk(256), gblk(512);

    // ---- adjacency: zero counters, bin edges, per-XCD scatter; weights
    zero_kernel<<<128, blk, 0, stream>>>((float4*)p1, 409600 / 16);
    bin_kernel<<<bblocks, blk, 0, stream>>>(esrc, edst, gcnt, bind, bins, E);
    scatter_fill_kernel<<<2048, blk, 0, stream>>>(gcnt, bind, bins, deg, col2);

    WPtrs wp;
    wp.w[0] = (const float*)d_in[3];  wp.w[1] = (const float*)d_in[5];  wp.w[2] = (const float*)d_in[6];
    wp.w[3] = (const float*)d_in[8];  wp.w[4] = (const float*)d_in[10]; wp.w[5] = (const float*)d_in[11];
    wp.w[6] = (const float*)d_in[13]; wp.w[7] = (const float*)d_in[15]; wp.w[8] = (const float*)d_in[16];
    split_weights_kernel<<<dim3(64, 9), blk, 0, stream>>>(wp, wbase);

    // ---- layer 0 (A = x in f32, converted in-flight)
    mfma_gemm_kernel<128, false, 2, true><<<gs, gblk, 0, stream>>>(
        x, nullptr, nullptr, nullptr, WT(0), nullptr, bp[0], nullptr, p4, N);
    mfma_gemm_kernel<128, true, 1, true><<<gd, gblk, 0, stream>>>(
        x, deg, col2, (const uint4*)p4, WT(1), WT(2), bn[0], nullptr, p2, N);

    // ---- layer 1 (A = p2 bf16)
    mfma_gemm_kernel<128, false, 2, false><<<gs, gblk, 0, stream>>>(
        p2, nullptr, nullptr, nullptr, WT(3), nullptr, bp[1], nullptr, p4, N);
    mfma_gemm_kernel<128, true, 1, false><<<gd, gblk, 0, stream>>>(
        p2, deg, col2, (const uint4*)p4, WT(4), WT(5), bn[1], nullptr, p0, N);

    // ---- layer 2 (A = p0 bf16), DO=64, fused log_softmax -> d_out
    mfma_gemm_kernel<128, false, 2, false><<<gs, gblk, 0, stream>>>(
        p0, nullptr, nullptr, nullptr, WT(6), nullptr, bp[2], nullptr, p4, N);
    mfma_gemm_kernel<64, true, 3, false><<<gd, gblk, 0, stream>>>(
        p0, deg, col2, (const uint4*)p4, WT(7), WT(8), bn[2], (float*)d_out, nullptr, N);
}

// Round 13
// 269.400 us; speedup vs baseline: 1.0076x; 1.0009x over previous
//
#include <hip/hip_runtime.h>
#include <cstddef>
#include <cstdint>

#define NNODES 100000
#define NEDGES 800000
#define CAP 32          // bucket capacity; in-degree ~ Poisson(8), P(>=33) ~ 1e-5
#define NXCD 8          // dst-space partitions == XCDs; 100000 % 8 == 0
#define NPB (NNODES / NXCD)   // 12500 nodes per bin
#define BINCAP 110592   // per-bin edge capacity; expected 100k +- 0.3k (+33 sigma)

typedef unsigned short u16;
typedef __attribute__((ext_vector_type(8))) short short8;     // 8 x bf16
typedef __attribute__((ext_vector_type(8))) _Float16 half8;   // 8 x f16
typedef __attribute__((ext_vector_type(4))) float f32x4;
typedef __attribute__((ext_vector_type(4))) int int4v;

__device__ __forceinline__ u16 f32_to_bf16(float f) {
    union { float f; uint32_t u; } v; v.f = f;
    uint32_t r = v.u + 0x7FFF + ((v.u >> 16) & 1);   // RNE; inputs finite
    return (u16)(r >> 16);
}
__device__ __forceinline__ u16 f32_to_f16(float f) {
    union { _Float16 h; u16 u; } v; v.h = (_Float16)f;
    return v.u;
}
// per-16-bit unsigned max on a packed word; for finite f16 >= 0 the unsigned
// bit-pattern order == IEEE order, so this is an exact packed f16 max.
__device__ __forceinline__ uint32_t pkmax(uint32_t a, uint32_t b) {
    uint32_t lo = max(a & 0xFFFFu, b & 0xFFFFu);
    uint32_t hi = max(a >> 16, b >> 16);
    return lo | (hi << 16);
}
__device__ __forceinline__ void agmax(uint4& a, uint4 v) {
    a.x = pkmax(a.x, v.x); a.y = pkmax(a.y, v.y);
    a.z = pkmax(a.z, v.z); a.w = pkmax(a.w, v.w);
}

// gather-max of one node row into 4 register chunks (lane owns chunk `sec+4k`
// of the 16-uint4 f16 row). 2-edge unrolled -> 8 outstanding 16B gathers.
__device__ __forceinline__ void gather_row(
    uint4 (&ag)[4], const uint4* __restrict__ m4,
    const int* __restrict__ deg, const int* __restrict__ col2, int row, int sec)
{
    int cnt = deg[row]; if (cnt > CAP) cnt = CAP;
    const int base = row * CAP;
    int e = 0;
    for (; e + 2 <= cnt; e += 2) {
        const uint4* q0 = m4 + (size_t)col2[base + e] * 16 + sec;
        const uint4* q1 = m4 + (size_t)col2[base + e + 1] * 16 + sec;
        uint4 v00 = q0[0], v01 = q0[4], v02 = q0[8], v03 = q0[12];
        uint4 v10 = q1[0], v11 = q1[4], v12 = q1[8], v13 = q1[12];
        agmax(ag[0], v00); agmax(ag[1], v01); agmax(ag[2], v02); agmax(ag[3], v03);
        agmax(ag[0], v10); agmax(ag[1], v11); agmax(ag[2], v12); agmax(ag[3], v13);
    }
    if (e < cnt) {
        const uint4* q0 = m4 + (size_t)col2[base + e] * 16 + sec;
        agmax(ag[0], q0[0]); agmax(ag[1], q0[4]); agmax(ag[2], q0[8]); agmax(ag[3], q0[12]);
    }
}

// ---------------------------------------------------------------------------
// zero-fill (avoids hipMemsetAsync under graph capture)
// ---------------------------------------------------------------------------
__global__ __launch_bounds__(256) void zero_kernel(float4* __restrict__ p, int n4) {
    int i = blockIdx.x * blockDim.x + threadIdx.x;
    const int stride = gridDim.x * blockDim.x;
    for (; i < n4; i += stride) p[i] = make_float4(0.f, 0.f, 0.f, 0.f);
}

// ---------------------------------------------------------------------------
// pass 1: bin edges by dst-range (LDS bin-sort per 1024-edge block, one
// global atomicAdd per bin per block, coalesced copy-out). Record order
// within a bin is scheduling-dependent -- fine, max is order-independent.
// ---------------------------------------------------------------------------
__global__ __launch_bounds__(256) void bin_kernel(
    const int* __restrict__ src, const int* __restrict__ dst,
    int* __restrict__ gcnt, int* __restrict__ bind, int* __restrict__ bins, int E)
{
    __shared__ int ld[1024], ls[1024];
    __shared__ int lcnt[8], lpre[8], lgb[8];
    const int tid = threadIdx.x;
    const int base = blockIdx.x * 1024;

    if (tid < 8) lcnt[tid] = 0;
    __syncthreads();

    int d[4], s[4], slot[4], b[4];
    int nv = 0;
    if (base + tid * 4 + 3 < E) {
        const int4v dd = *(const int4v*)&dst[base + tid * 4];
        const int4v ss = *(const int4v*)&src[base + tid * 4];
#pragma unroll
        for (int j = 0; j < 4; ++j) { d[j] = dd[j]; s[j] = ss[j]; }
        nv = 4;
    } else {
        for (int j = 0; j < 4; ++j) {
            const int idx = base + tid * 4 + j;
            if (idx < E) { d[nv] = dst[idx]; s[nv] = src[idx]; ++nv; }
        }
    }
#pragma unroll 4
    for (int j = 0; j < nv; ++j) {
        b[j] = d[j] / NPB;
        slot[j] = atomicAdd(&lcnt[b[j]], 1);
    }
    __syncthreads();
    if (tid == 0) {
        int run = 0;
#pragma unroll
        for (int k = 0; k < 8; ++k) { lpre[k] = run; run += lcnt[k]; }
    }
    __syncthreads();
#pragma unroll 4
    for (int j = 0; j < nv; ++j) {
        const int p = lpre[b[j]] + slot[j];
        ld[p] = d[j]; ls[p] = s[j];
    }
    if (tid < 8 && lcnt[tid] > 0) lgb[tid] = atomicAdd(&gcnt[tid], lcnt[tid]);
    __syncthreads();
    const int total = lpre[7] + lcnt[7];
    for (int i = tid; i < total; i += 256) {
        const int d_ = ld[i];
        const int b_ = d_ / NPB;
        const int g = lgb[b_] + (i - lpre[b_]);
        if (g < BINCAP) {           // clamp: memory safety only
            bind[b_ * BINCAP + g] = d_;
            bins[b_ * BINCAP + g] = ls[i];
        }
    }
}

// ---------------------------------------------------------------------------
// pass 2: XCD-group i (blockIdx%8==i) consumes only bin i: contiguous read,
// scatter into its L2-resident col2 slice. Single-writer-XCD.
// ---------------------------------------------------------------------------
__global__ __launch_bounds__(256) void scatter_fill_kernel(
    const int* __restrict__ gcnt,
    const int* __restrict__ bind, const int* __restrict__ bins,
    int* __restrict__ deg, int* __restrict__ col2)
{
    const int xcd  = blockIdx.x & (NXCD - 1);
    const int grp  = blockIdx.x >> 3;
    const int ngrp = gridDim.x >> 3;
    int cnt = gcnt[xcd]; if (cnt > BINCAP) cnt = BINCAP;
    const int* bd = bind + xcd * BINCAP;
    const int* bs = bins + xcd * BINCAP;
    for (int i = grp * 256 + threadIdx.x; i < cnt; i += ngrp * 256) {
        const int d = bd[i];
        const int r = atomicAdd(&deg[d], 1);
        if (r < CAP) col2[d * CAP + r] = bs[i];   // clamp: memory safety only
    }
}

// ---------------------------------------------------------------------------
// transpose + round all 9 weight matrices: W[K=128][DO] f32 -> WT[DO][128] u16.
// widx 0=Wp0 1=Ws0 2=Wn0 3=Wp1 4=Ws1 5=Wn1 6=Wp2 7=Ws2(DO64) 8=Wn2(DO64).
// Wn matrices (2,5,8) -> f16 (multiply the f16 agg); others -> bf16.
// ---------------------------------------------------------------------------
struct WPtrs { const float* w[9]; };

__global__ __launch_bounds__(256) void split_weights_kernel(WPtrs p, u16* __restrict__ wbase)
{
    const int idx = blockIdx.x * 256 + threadIdx.x;
    const int w = blockIdx.y;
    const int DO_ = (w >= 7) ? 64 : 128;
    if (idx >= 128 * DO_) return;
    const float v = p.w[w][idx];
    const int k = idx / DO_;
    const int c = idx - k * DO_;
    const bool use_f16 = (w == 2 || w == 5 || w == 8);
    wbase[w * 32768 + c * 128 + k] = use_f16 ? f32_to_f16(v) : f32_to_bf16(v);
}

// ---------------------------------------------------------------------------
// MFMA GEMM with optional fused gather-max neighbor operand.
//   out[N,DO] = relu( A@Wa (+ segmax(m)@Wb) + bias ), K=128.
// A: bf16 [N][128] (or f32 when AF32: converted in-flight, bit-identical to
// the old cast kernel). W: transposed [DO][128] u16 in LDS.
// DUAL: C-fragment built by in-register gather-max over in-edges (exact f16
// max via pkmax); waves then handle 1 M-tile (16 rows) to keep VGPRs in
// budget; single keeps 2 M-tiles.
// OUT_MODE: 1 = bf16 plane, 2 = f16 plane, 3 = fused log_softmax -> f32.
// ---------------------------------------------------------------------------
template<int DO, bool DUAL, int OUT_MODE, bool AF32>
__global__ __launch_bounds__(512, 4) void mfma_gemm_kernel(
    const void* __restrict__ Av,
    const int* __restrict__ deg, const int* __restrict__ col2,
    const uint4* __restrict__ m4,
    const u16* __restrict__ WaT, const u16* __restrict__ WbT,
    const float* __restrict__ bias,
    float* __restrict__ outF, u16* __restrict__ outU, int N)
{
    constexpr int CT = DO / 16;
    constexpr int MT = DUAL ? 1 : 2;              // M-tiles per wave
    constexpr int WS = 136;                       // padded u16 row stride
    __shared__ u16 sW[(DUAL ? 2 : 1) * DO * WS];

    const int tid = threadIdx.x;

    // ---- stage W (transposed [DO][128]) into LDS
    for (int i = tid; i < DO * 16; i += 512) {
        const int r = i >> 4;
        const int c = (i & 15) << 3;
        *(short8*)&sW[r * WS + c] = *(const short8*)&WaT[r * 128 + c];
        if constexpr (DUAL)
            *(short8*)&sW[DO * WS + r * WS + c] = *(const short8*)&WbT[r * 128 + c];
    }

    const int lane = tid & 63;
    const int wid  = tid >> 6;                    // 0..7
    const int l15  = lane & 15;
    const int sec  = lane >> 4;                   // 0..3
    const int lk   = sec << 3;                    // 0,8,16,24
    const int row0 = blockIdx.x * (128 * MT) + wid * (16 * MT);

    int rc[MT], aoff[MT];
#pragma unroll
    for (int m = 0; m < MT; ++m) {
        int r = row0 + m * 16 + l15; if (r > N - 1) r = N - 1;
        rc[m] = r;
        aoff[m] = r * 128 + lk;
    }

    // ---- fused gather-max (DUAL): C-fragments for this lane's row
    uint4 ag[MT][4];
    if constexpr (DUAL) {
#pragma unroll
        for (int m = 0; m < MT; ++m)
#pragma unroll
            for (int k = 0; k < 4; ++k) ag[m][k] = make_uint4(0, 0, 0, 0);
#pragma unroll
        for (int m = 0; m < MT; ++m)
            gather_row(ag[m], m4, deg, col2, rc[m], sec);
    }

    f32x4 acc[MT][CT];
#pragma unroll
    for (int m = 0; m < MT; ++m)
#pragma unroll
        for (int c = 0; c < CT; ++c) acc[m][c] = (f32x4){0.f, 0.f, 0.f, 0.f};

    __syncthreads();

#pragma unroll
    for (int k = 0; k < 4; ++k) {
        const int ko = 32 * k;
        short8 ah[MT];
#pragma unroll
        for (int m = 0; m < MT; ++m) {
            if constexpr (AF32) {
                const float* pa = (const float*)Av + aoff[m] + ko;
                f32x4 a = *(const f32x4*)pa;
                f32x4 b = *(const f32x4*)(pa + 4);
#pragma unroll
                for (int j = 0; j < 4; ++j) {
                    ah[m][j]     = (short)f32_to_bf16(a[j]);
                    ah[m][j + 4] = (short)f32_to_bf16(b[j]);
                }
            } else {
                ah[m] = *(const short8*)((const u16*)Av + aoff[m] + ko);
            }
        }
        half8 ch[MT];
        if constexpr (DUAL) {
#pragma unroll
            for (int m = 0; m < MT; ++m) {
                union { uint4 u; half8 h; } t; t.u = ag[m][k];
                ch[m] = t.h;
            }
        }
#pragma unroll
        for (int ct = 0; ct < CT; ++ct) {
            const int wb = (ct * 16 + l15) * WS + lk + ko;
            short8 wh = *(const short8*)&sW[wb];
#pragma unroll
            for (int m = 0; m < MT; ++m)
                acc[m][ct] = __builtin_amdgcn_mfma_f32_16x16x32_bf16(ah[m], wh, acc[m][ct], 0, 0, 0);
            if constexpr (DUAL) {
                half8 vh = *(const half8*)&sW[DO * WS + wb];
#pragma unroll
                for (int m = 0; m < MT; ++m)
                    acc[m][ct] = __builtin_amdgcn_mfma_f32_16x16x32_f16(ch[m], vh, acc[m][ct], 0, 0, 0);
            }
        }
    }

    // ---- epilogue: D frag row = sec*4 + j, col = l15 (m89 layout)
    float bv[CT];
#pragma unroll
    for (int ct = 0; ct < CT; ++ct) bv[ct] = bias[ct * 16 + l15];

    const int jrow = sec << 2;
#pragma unroll
    for (int m = 0; m < MT; ++m) {
#pragma unroll
        for (int j = 0; j < 4; ++j) {
            const int r = row0 + m * 16 + jrow + j;
            if constexpr (OUT_MODE == 3) {
                // fused log_softmax over DO=64: row's 64 values live in the
                // 16 lanes sharing sec -> shfl_xor 1,2,4,8 reduce.
                float v[CT];
                float mx = 0.f;   // post-relu values >= 0
#pragma unroll
                for (int ct = 0; ct < CT; ++ct) {
                    v[ct] = fmaxf(acc[m][ct][j] + bv[ct], 0.f);
                    mx = fmaxf(mx, v[ct]);
                }
#pragma unroll
                for (int off = 1; off < 16; off <<= 1) mx = fmaxf(mx, __shfl_xor(mx, off));
                float s = 0.f;
#pragma unroll
                for (int ct = 0; ct < CT; ++ct) s += __expf(v[ct] - mx);
#pragma unroll
                for (int off = 1; off < 16; off <<= 1) s += __shfl_xor(s, off);
                const float lse = mx + __logf(s);
                if (r < N) {
#pragma unroll
                    for (int ct = 0; ct < CT; ++ct)
                        outF[(size_t)r * DO + ct * 16 + l15] = v[ct] - lse;
                }
            } else if (r < N) {
#pragma unroll
                for (int ct = 0; ct < CT; ++ct) {
                    float v = fmaxf(acc[m][ct][j] + bv[ct], 0.f);
                    const size_t o = (size_t)r * DO + ct * 16 + l15;
                    if constexpr (OUT_MODE == 1) {
                        outU[o] = f32_to_bf16(v);
                    } else {
                        outU[o] = f32_to_f16(v);
                    }
                }
            }
        }
    }
}

// ---------------------------------------------------------------------------
extern "C" void kernel_launch(void* const* d_in, const int* in_sizes, int n_in,
                              void* d_out, int out_size, void* d_ws, size_t ws_size,
                              hipStream_t stream)
{
    const int N = NNODES, E = NEDGES;
    const float* x  = (const float*)d_in[0];
    const int* esrc = (const int*)d_in[1];
    const int* edst = (const int*)d_in[2];
    const float* bp[3] = {(const float*)d_in[4], (const float*)d_in[9],  (const float*)d_in[14]};
    const float* bn[3] = {(const float*)d_in[7], (const float*)d_in[12], (const float*)d_in[17]};

    // ALL scratch in d_ws (153.6 MB = 6 planes of 25.6 MB); d_out is written
    // only by the final fused GEMM -> no race, no copies.
    char* ws = (char*)d_ws;
    const size_t P = (size_t)N * 128 * 2;
    u16* p0 = (u16*)(ws);                    // h ping (bf16)
    char* p1 = ws + P;                       // deg(+gcnt) | col2
    u16* p2 = (u16*)(ws + 2 * P);            // h pong (bf16)
    char* p3 = ws + 3 * P;                   // bind | bins
    u16* p4 = (u16*)(ws + 4 * P);            // m (f16 [N][128])
    u16* p5 = (u16*)(ws + 5 * P);            // weights (9 x 64 KB)

    int* deg  = (int*)p1;                    // 100000 ints
    int* gcnt = (int*)(p1 + 400000);         // 8 ints (inside zeroed 409600 B)
    int* col2 = (int*)(p1 + 409600);         // N*CAP ints = 12.8 MB
    int* bind = (int*)p3;                    // 8*BINCAP ints = 3.54 MB
    int* bins = bind + 8 * BINCAP;           // 3.54 MB
    u16* wbase = p5;
    auto WT = [&](int i) { return wbase + i * 32768; };

    const int gs = (N + 255) / 256;          // 391 single-GEMM blocks (256 rows)
    const int gd = (N + 127) / 128;          // 782 dual-GEMM blocks (128 rows)
    const int bblocks = (E + 1023) / 1024;   // 782
    dim3 blk(256), gblk(512);

    // ---- adjacency: zero counters, bin edges, per-XCD scatter; weights
    zero_kernel<<<128, blk, 0, stream>>>((float4*)p1, 409600 / 16);
    bin_kernel<<<bblocks, blk, 0, stream>>>(esrc, edst, gcnt, bind, bins, E);
    scatter_fill_kernel<<<2048, blk, 0, stream>>>(gcnt, bind, bins, deg, col2);

    WPtrs wp;
    wp.w[0] = (const float*)d_in[3];  wp.w[1] = (const float*)d_in[5];  wp.w[2] = (const float*)d_in[6];
    wp.w[3] = (const float*)d_in[8];  wp.w[4] = (const float*)d_in[10]; wp.w[5] = (const float*)d_in[11];
    wp.w[6] = (const float*)d_in[13]; wp.w[7] = (const float*)d_in[15]; wp.w[8] = (const float*)d_in[16];
    split_weights_kernel<<<dim3(64, 9), blk, 0, stream>>>(wp, wbase);

    // ---- layer 0 (A = x in f32, converted in-flight)
    mfma_gemm_kernel<128, false, 2, true><<<gs, gblk, 0, stream>>>(
        x, nullptr, nullptr, nullptr, WT(0), nullptr, bp[0], nullptr, p4, N);
    mfma_gemm_kernel<128, true, 1, true><<<gd, gblk, 0, stream>>>(
        x, deg, col2, (const uint4*)p4, WT(1), WT(2), bn[0], nullptr, p2, N);

    // ---- layer 1 (A = p2 bf16)
    mfma_gemm_kernel<128, false, 2, false><<<gs, gblk, 0, stream>>>(
        p2, nullptr, nullptr, nullptr, WT(3), nullptr, bp[1], nullptr, p4, N);
    mfma_gemm_kernel<128, true, 1, false><<<gd, gblk, 0, stream>>>(
        p2, deg, col2, (const uint4*)p4, WT(4), WT(5), bn[1], nullptr, p0, N);

    // ---- layer 2 (A = p0 bf16), DO=64, fused log_softmax -> d_out
    mfma_gemm_kernel<128, false, 2, false><<<gs, gblk, 0, stream>>>(
        p0, nullptr, nullptr, nullptr, WT(6), nullptr, bp[2], nullptr, p4, N);
    mfma_gemm_kernel<64, true, 3, false><<<gd, gblk, 0, stream>>>(
        p0, deg, col2, (const uint4*)p4, WT(7), WT(8), bn[2], (float*)d_out, nullptr, N);
}